// Round 15
// baseline (1173.444 us; speedup 1.0000x reference)
//
#include <hip/hip_runtime.h>
#include <cstdint>
#include <cstddef>

typedef unsigned short u16;
typedef __attribute__((ext_vector_type(8))) __bf16 bf16x8;
typedef __attribute__((ext_vector_type(4))) float f32x4;

typedef __attribute__((address_space(1))) const void GAS;
typedef __attribute__((address_space(3))) void LAS;

__device__ __forceinline__ void gld_lds16(const void* g, void* l) {
  __builtin_amdgcn_global_load_lds((GAS*)g, (LAS*)l, 16, 0, 0);
}

__device__ __forceinline__ u16 f2bf(float f) {
  union { float f; unsigned u; } x; x.f = f;
  unsigned r = x.u + 0x7FFFu + ((x.u >> 16) & 1u);
  return (u16)(r >> 16);
}
__device__ __forceinline__ float bf2f(u16 s) {
  union { unsigned u; float f; } x; x.u = ((unsigned)s) << 16;
  return x.f;
}
__device__ __forceinline__ f32x4 mfma16(bf16x8 a, bf16x8 b, f32x4 c) {
  return __builtin_amdgcn_mfma_f32_16x16x32_bf16(a, b, c, 0, 0, 0);
}

// ---------------- small prep kernels ----------------

__global__ void selmap_k(const int* __restrict__ nzb, int* __restrict__ map) {
  int t = threadIdx.x;            // 1024 threads
  map[t] = -1;
  __syncthreads();
  if (t < 512) map[nzb[t]] = t;
}

__global__ __launch_bounds__(256) void castw_k(const float* __restrict__ in,
                                               u16* __restrict__ out, int n4) {
  int i = blockIdx.x * 256 + threadIdx.x;
  if (i >= n4) return;
  float4 v = ((const float4*)in)[i];
  u16 o[4] = {f2bf(v.x), f2bf(v.y), f2bf(v.z), f2bf(v.w)};
  ((uint2*)out)[i] = *(uint2*)o;
}

__global__ __launch_bounds__(256) void adaln_k(const float* __restrict__ c,
    const float* __restrict__ w, const float* __restrict__ b, float* __restrict__ mods) {
  int j = blockIdx.x * 256 + threadIdx.x;  // 0..3071
  int bt = blockIdx.y;
  const float4* cr = (const float4*)(c + bt * 512);
  const float4* wr = (const float4*)(w + (size_t)j * 512);
  float s = 0.f;
  #pragma unroll 4
  for (int k = 0; k < 128; ++k) {
    float4 a = wr[k], q = cr[k];
    s += a.x * q.x + a.y * q.y + a.z * q.z + a.w * q.w;
  }
  mods[bt * 3072 + j] = s + b[j];
}

// rope the shared empty-block K, copy/transpose empty V
__global__ __launch_bounds__(256) void kvempty_k(const float* __restrict__ kve,
    const float* __restrict__ cT, const float* __restrict__ sT,
    u16* __restrict__ kempty, u16* __restrict__ vTempty) {
  int T = blockIdx.x * 256 + threadIdx.x;  // 32768
  int h = T >> 12, p = (T >> 6) & 63, d = T & 63;
  float kv = kve[p * 1024 + h * 64 + d];
  float pv = kve[p * 1024 + h * 64 + (d ^ 32)];
  float cs = cT[p * 64 + d], sn = sT[p * 64 + d];
  float r = kv * cs + ((d < 32) ? -pv : pv) * sn;
  kempty[(h * 64 + p) * 64 + d] = f2bf(r);
  vTempty[(h * 64 + d) * 64 + p] = f2bf(kve[p * 1024 + 512 + h * 64 + d]);
}

// ---------------- LN1 + modulate + block-gather, 4 rows/wave ----------------

__global__ __launch_bounds__(256) void ln1_k(const float* __restrict__ x,
    const float* __restrict__ nw, const float* __restrict__ mods,
    const int* __restrict__ nzb, u16* __restrict__ xm) {
  int row0 = blockIdx.x * 16 + (threadIdx.x >> 6) * 4;  // p aligned to 4
  int t = threadIdx.x & 63;
  int sel = row0 >> 6, p = row0 & 63;
  int g = nzb[sel];
  int bt = g >> 9, blk = g & 511;
  int s = (blk >> 6) * 4096 + (p >> 4) * 1024 + ((blk >> 3) & 7) * 128
        + ((p >> 2) & 3) * 32 + (blk & 7) * 4 + (p & 3);
  const float* src = x + ((size_t)bt * 32768 + s) * 512;   // rows s..s+3 consecutive
  int d0 = t * 8;
  float v[4][8];
  #pragma unroll
  for (int rr = 0; rr < 4; ++rr) {
    float4 a = *(const float4*)(src + rr * 512 + d0);
    float4 b = *(const float4*)(src + rr * 512 + d0 + 4);
    v[rr][0] = a.x; v[rr][1] = a.y; v[rr][2] = a.z; v[rr][3] = a.w;
    v[rr][4] = b.x; v[rr][5] = b.y; v[rr][6] = b.z; v[rr][7] = b.w;
  }
  const float* mb = mods + bt * 3072;
  float wv[8], sh[8], sc[8];
  #pragma unroll
  for (int j = 0; j < 8; ++j) {
    wv[j] = nw[d0 + j]; sh[j] = mb[d0 + j]; sc[j] = mb[512 + d0 + j];
  }
  #pragma unroll
  for (int rr = 0; rr < 4; ++rr) {
    float sum = 0.f, sq = 0.f;
    #pragma unroll
    for (int j = 0; j < 8; ++j) { sum += v[rr][j]; sq += v[rr][j] * v[rr][j]; }
    #pragma unroll
    for (int m = 1; m < 64; m <<= 1) {
      sum += __shfl_xor(sum, m, 64);
      sq  += __shfl_xor(sq, m, 64);
    }
    float mean = sum * (1.f / 512.f);
    float var = sq * (1.f / 512.f) - mean * mean;
    float rstd = rsqrtf(var + 1e-5f);
    u16 o[8];
    #pragma unroll
    for (int j = 0; j < 8; ++j) {
      float xn = (v[rr][j] - mean) * rstd * wv[j];
      o[j] = f2bf(xn * (1.f + sc[j]) + sh[j]);
    }
    *(uint4*)(xm + (size_t)(row0 + rr) * 512 + d0) = *(uint4*)o;
  }
}

// ---------------- 128x128 bf16 GEMM, BK=32, dbuf, counted vmcnt, 5 blocks/CU ----------------
// 16x16x32 MFMA (conflict-free LDS pattern; 32x32x16 at BK=32 is intrinsically
// 4-way bank-conflicted -- R14 measured 1.7e7 conflicts, regressed).
// NON-CHAINED (bn-fast tile order keeps A-panel sharers concurrently resident
// -> L2-hit reuse). XCD-swizzled tile id.
// Swizzle: chunk j of row r stored at pos = j ^ ((r>>1)&3)  (2-way max = free).
// (256,5): LDS 32K*5 = 160K exactly; VGPR cap ~96 >> 56 used -> no spill.
// EPI: 0 store bf16; 2 +bias+sigmoid-gelu bf16; 3 +bias, out = bf2f(x1)+gate*val

template <int EPI>
__global__ __launch_bounds__(256, 5) void gemm128(const u16* __restrict__ A,
    const u16* __restrict__ W, int M, int N, int K, void* __restrict__ outp,
    const float* __restrict__ bias, const u16* __restrict__ x1,
    const float* __restrict__ mods, int NB) {
  __shared__ u16 L[2][8192];             // [buf][A:4096 | B:4096]
  const int nwg = gridDim.x;
  const int cpx = nwg >> 3;
  const int tile = ((int)blockIdx.x & 7) * cpx + ((int)blockIdx.x >> 3);
  const int bm = (tile / NB) * 128, bn = (tile % NB) * 128;
  const int tid = threadIdx.x;
  const int w = tid >> 6, l = tid & 63, lr = l & 15, lg = l >> 4;
  const int wr = w >> 1, wc = w & 1;

  // staging: slot s -> row s>>2, pos s&3; global chunk j = (s&3) ^ ((s>>3)&3)
  const int s0 = tid, s1 = 256 + tid;
  const int rA0 = s0 >> 2, j0 = (s0 & 3) ^ ((s0 >> 3) & 3);
  const int rA1 = s1 >> 2, j1 = (s1 & 3) ^ ((s1 >> 3) & 3);
  const u16* gA0 = A + (size_t)(bm + rA0) * K + j0 * 8;
  const u16* gA1 = A + (size_t)(bm + rA1) * K + j1 * 8;
  const u16* gB0 = W + (size_t)(bn + rA0) * K + j0 * 8;
  const u16* gB1 = W + (size_t)(bn + rA1) * K + j1 * 8;

  f32x4 acc[4][4];
  #pragma unroll
  for (int i = 0; i < 4; ++i)
    #pragma unroll
    for (int j = 0; j < 4; ++j) acc[i][j] = (f32x4){0.f, 0.f, 0.f, 0.f};

  auto STAGE = [&](int kt, int buf) {
    u16* lb = &L[buf][0];
    gld_lds16(gA0 + (size_t)kt * 32, lb + s0 * 8);
    gld_lds16(gA1 + (size_t)kt * 32, lb + s1 * 8);
    gld_lds16(gB0 + (size_t)kt * 32, lb + 4096 + s0 * 8);
    gld_lds16(gB1 + (size_t)kt * 32, lb + 4096 + s1 * 8);
  };
  auto COMPUTE = [&](int buf) {
    const u16* base = &L[buf][0];
    bf16x8 bfr[4];
    #pragma unroll
    for (int nf = 0; nf < 4; ++nf) {
      int rB = wc * 64 + nf * 16 + lr;
      bfr[nf] = *(const bf16x8*)(base + 4096 + rB * 32 + ((lg ^ ((rB >> 1) & 3)) << 3));
    }
    __builtin_amdgcn_s_setprio(1);
    #pragma unroll
    for (int mf = 0; mf < 4; ++mf) {
      int rA = wr * 64 + mf * 16 + lr;
      bf16x8 a = *(const bf16x8*)(base + rA * 32 + ((lg ^ ((rA >> 1) & 3)) << 3));
      #pragma unroll
      for (int nf = 0; nf < 4; ++nf)
        acc[mf][nf] = mfma16(a, bfr[nf], acc[mf][nf]);
    }
    __builtin_amdgcn_s_setprio(0);
  };

  const int NT = K >> 5;
  STAGE(0, 0);
  for (int t = 0; t < NT; ++t) {
    if (t + 1 < NT) {
      STAGE(t + 1, (t + 1) & 1);
      asm volatile("s_waitcnt vmcnt(4)" ::: "memory");
    } else {
      asm volatile("s_waitcnt vmcnt(0)" ::: "memory");
    }
    __builtin_amdgcn_sched_barrier(0);
    __builtin_amdgcn_s_barrier();
    asm volatile("" ::: "memory");
    COMPUTE(t & 1);
    asm volatile("" ::: "memory");
    __builtin_amdgcn_s_barrier();
    __builtin_amdgcn_sched_barrier(0);
  }

  const int row0 = bm + wr * 64, col0 = bn + wc * 64;
  #pragma unroll
  for (int mf = 0; mf < 4; ++mf) {
    #pragma unroll
    for (int nf = 0; nf < 4; ++nf) {
      #pragma unroll
      for (int j = 0; j < 4; ++j) {
        int row = row0 + mf * 16 + lg * 4 + j;
        int col = col0 + nf * 16 + lr;
        float v = acc[mf][nf][j];
        if constexpr (EPI == 0) {
          ((u16*)outp)[(size_t)row * N + col] = f2bf(v);
        } else if constexpr (EPI == 2) {
          v += bias[col];
          // sigmoid-GELU: v*sigmoid(1.702v) (|diff| vs tanh-GELU < ~0.02)
          float sg = 1.f / (1.f + __expf(-1.702f * v));
          ((u16*)outp)[(size_t)row * N + col] = f2bf(v * sg);
        } else {
          v += bias[col];
          int bt = row >> 15;
          float gate = mods[bt * 3072 + 2560 + col];
          ((float*)outp)[(size_t)row * 512 + col] =
              bf2f(x1[(size_t)row * 512 + col]) + gate * v;
        }
      }
    }
  }
}

// ---------------- rope + pack q/k into [sel][h][p][d] ----------------

__global__ __launch_bounds__(256) void ropepack_k(const u16* __restrict__ qkv,
    const float* __restrict__ cq, const float* __restrict__ sq,
    const float* __restrict__ ck, const float* __restrict__ sk,
    u16* __restrict__ qb, u16* __restrict__ kb) {
  int T = blockIdx.x * 256 + threadIdx.x;  // 32768 * 128
  int row = T >> 7, oct = T & 127;
  int c0 = oct * 8;
  int sel = row >> 6, p = row & 63;
  int isk = (c0 >= 512);
  int chn = c0 & 511;
  int h = chn >> 6, d0 = chn & 63;
  int lower = (d0 < 32);
  const u16* base = qkv + (size_t)row * 1536 + (isk ? 512 : 0) + h * 64;
  u16 vm[8], vp[8];
  *(uint4*)vm = *(const uint4*)(base + d0);
  *(uint4*)vp = *(const uint4*)(base + (d0 ^ 32));
  const float* cT = (isk ? ck : cq) + p * 64 + d0;
  const float* sT = (isk ? sk : sq) + p * 64 + d0;
  float scale = isk ? 1.f : 0.125f;  // fold 1/sqrt(dh) into q
  u16 o[8];
  #pragma unroll
  for (int j = 0; j < 8; ++j) {
    float a = bf2f(vm[j]), b = bf2f(vp[j]);
    float r = a * cT[j] + (lower ? -b : b) * sT[j];
    o[j] = f2bf(r * scale);
  }
  u16* dst = (isk ? kb : qb) + (((size_t)sel * 8 + h) * 64 + p) * 64 + d0;
  *(uint4*)dst = *(uint4*)o;
}

// ---------------- v transpose: qkv v-part -> vT [sel][h][d][p] ----------------

__global__ __launch_bounds__(256) void vtrans_k(const u16* __restrict__ qkv,
                                                u16* __restrict__ vT) {
  __shared__ u16 tb[64 * 65];
  int sel = blockIdx.x >> 3, h = blockIdx.x & 7;
  int tid = threadIdx.x;
  int p = tid >> 2, q16 = (tid & 3) * 16;
  const u16* src = qkv + (size_t)(sel * 64 + p) * 1536 + 1024 + h * 64 + q16;
  u16 ld[16];
  *(uint4*)&ld[0] = *(const uint4*)src;
  *(uint4*)&ld[8] = *(const uint4*)(src + 8);
  #pragma unroll
  for (int j = 0; j < 16; ++j) tb[p * 65 + q16 + j] = ld[j];
  __syncthreads();
  int d = tid >> 2, po = (tid & 3) * 16;
  u16 o[16];
  #pragma unroll
  for (int j = 0; j < 16; ++j) o[j] = tb[(po + j) * 65 + d];
  u16* dst = vT + (((size_t)sel * 8 + h) * 64 + d) * 64 + po;
  *(uint4*)dst = *(uint4*)&o[0];
  *(uint4*)(dst + 8) = *(uint4*)&o[8];
}

// ---------------- attention: flash over neighbors, K staged in LDS ----------------
// R3-proven structure: K double-buffered in LDS (XOR-swizzled via pre-swizzled
// global src), counted vmcnt(2), raw barriers; V direct-global; online softmax.
// (256,4) ONLY: any higher min-waves bound spills (R10: (256,8) VGPR->32;
// R12: (256,6) VGPR->40, scratch FETCH 304MB). Natural VGPR=64 at (256,4).

__global__ __launch_bounds__(256, 4) void attn_k(const u16* __restrict__ qbuf,
    const u16* __restrict__ kfull, const u16* __restrict__ vT,
    const u16* __restrict__ kempty, const u16* __restrict__ vTempty,
    const int* __restrict__ nbrs, const int* __restrict__ selmap,
    u16* __restrict__ attnout) {
  __shared__ u16 KB[2][4096];        // 16 KiB, K tile [64 k][64 d], chunk^=(row&7)
  __shared__ u16 Pl[4][16][72];      // 9.2 KiB, per-wave P
  int bid = blockIdx.x;
  int swz = (bid & 7) * 512 + (bid >> 3);   // XCD-chunked (4096 % 8 == 0, bijective)
  int sel = swz >> 3, h = swz & 7;
  int tid = threadIdx.x;
  int w = tid >> 6, l = tid & 63, lr = l & 15, lg = l >> 4;

  int mmv[7];
  #pragma unroll
  for (int n = 0; n < 7; ++n) mmv[n] = selmap[nbrs[sel * 7 + n]];

  const u16* qg = qbuf + (((size_t)sel * 8 + h) * 64 + w * 16) * 64;
  bf16x8 qf0 = *(const bf16x8*)(qg + lr * 64 + lg * 8);
  bf16x8 qf1 = *(const bf16x8*)(qg + lr * 64 + 32 + lg * 8);

  // staging: LDS slot s = i*256+tid holds K[row=s>>3][chunk=(s&7)^(row&7)]
  int srow = tid >> 3;
  int soff = srow * 64 + (((tid & 7) ^ (srow & 7)) << 3);  // u16 units; i=1: +2048
  size_t hoff = (size_t)h * 4096;

  {
    const u16* kp = (mmv[0] >= 0) ? kfull + (size_t)mmv[0] * 32768 + hoff
                                  : kempty + hoff;
    gld_lds16(kp + soff, &KB[0][w * 512]);
    gld_lds16(kp + soff + 2048, &KB[0][2048 + w * 512]);
  }

  f32x4 o[4];
  float mrun[4], lrun[4];
  #pragma unroll
  for (int ct = 0; ct < 4; ++ct) o[ct] = (f32x4){0.f, 0.f, 0.f, 0.f};
  #pragma unroll
  for (int r = 0; r < 4; ++r) { mrun[r] = -1e30f; lrun[r] = 0.f; }

  #pragma unroll
  for (int n = 0; n < 7; ++n) {
    if (n < 6) {
      const u16* kp = (mmv[n + 1] >= 0) ? kfull + (size_t)mmv[n + 1] * 32768 + hoff
                                        : kempty + hoff;
      int b = (n + 1) & 1;
      gld_lds16(kp + soff, &KB[b][w * 512]);
      gld_lds16(kp + soff + 2048, &KB[b][2048 + w * 512]);
      asm volatile("s_waitcnt vmcnt(2)" ::: "memory");
    } else {
      asm volatile("s_waitcnt vmcnt(0)" ::: "memory");
    }
    __builtin_amdgcn_s_barrier();
    __builtin_amdgcn_sched_barrier(0);

    const u16* kl = &KB[n & 1][0];
    const u16* vp = (mmv[n] >= 0) ? vT + (size_t)mmv[n] * 32768 + hoff
                                  : vTempty + hoff;
    // QK^T for this neighbor
    f32x4 s4[4];
    int xr = lr & 7;
    #pragma unroll
    for (int ct = 0; ct < 4; ++ct) {
      int row = ct * 16 + lr;
      bf16x8 b0 = *(const bf16x8*)(kl + row * 64 + ((lg ^ xr) << 3));
      bf16x8 b1 = *(const bf16x8*)(kl + row * 64 + (((lg + 4) ^ xr) << 3));
      f32x4 z = (f32x4){0.f, 0.f, 0.f, 0.f};
      z = mfma16(qf0, b0, z);
      z = mfma16(qf1, b1, z);
      s4[ct] = z;
    }
    // online softmax update
    float rmax[4], sc[4], rs[4];
    #pragma unroll
    for (int r = 0; r < 4; ++r)
      rmax[r] = fmaxf(fmaxf(s4[0][r], s4[1][r]), fmaxf(s4[2][r], s4[3][r]));
    #pragma unroll
    for (int r = 0; r < 4; ++r) {
      #pragma unroll
      for (int ms = 1; ms < 16; ms <<= 1)
        rmax[r] = fmaxf(rmax[r], __shfl_xor(rmax[r], ms, 64));
      float mn = fmaxf(mrun[r], rmax[r]);
      sc[r] = __expf(mrun[r] - mn);
      mrun[r] = mn;
      rs[r] = 0.f;
    }
    #pragma unroll
    for (int ct = 0; ct < 4; ++ct)
      #pragma unroll
      for (int r = 0; r < 4; ++r) {
        float e = __expf(s4[ct][r] - mrun[r]);
        s4[ct][r] = e;
        rs[r] += e;
      }
    #pragma unroll
    for (int r = 0; r < 4; ++r) {
      #pragma unroll
      for (int ms = 1; ms < 16; ms <<= 1) rs[r] += __shfl_xor(rs[r], ms, 64);
      lrun[r] = lrun[r] * sc[r] + rs[r];
    }
    #pragma unroll
    for (int ct = 0; ct < 4; ++ct)
      #pragma unroll
      for (int r = 0; r < 4; ++r) o[ct][r] *= sc[r];
    // P -> LDS (wave-local), then PV with direct-global V
    #pragma unroll
    for (int ct = 0; ct < 4; ++ct)
      #pragma unroll
      for (int r = 0; r < 4; ++r)
        Pl[w][lg * 4 + r][ct * 16 + lr] = f2bf(s4[ct][r]);
    asm volatile("s_waitcnt lgkmcnt(0)" ::: "memory");
    __builtin_amdgcn_sched_barrier(0);
    bf16x8 pa0 = *(const bf16x8*)&Pl[w][lr][lg * 8];
    bf16x8 pa1 = *(const bf16x8*)&Pl[w][lr][32 + lg * 8];
    #pragma unroll
    for (int ct = 0; ct < 4; ++ct) {
      bf16x8 v0 = *(const bf16x8*)(vp + (ct * 16 + lr) * 64 + lg * 8);
      bf16x8 v1 = *(const bf16x8*)(vp + (ct * 16 + lr) * 64 + 32 + lg * 8);
      o[ct] = mfma16(pa0, v0, o[ct]);
      o[ct] = mfma16(pa1, v1, o[ct]);
    }
    asm volatile("" ::: "memory");
    __builtin_amdgcn_s_barrier();     // KB[n&1] free for restage at iter n+1
    __builtin_amdgcn_sched_barrier(0);
  }

  float inv[4];
  #pragma unroll
  for (int r = 0; r < 4; ++r) inv[r] = 1.f / lrun[r];
  #pragma unroll
  for (int ct = 0; ct < 4; ++ct)
    #pragma unroll
    for (int r = 0; r < 4; ++r) {
      int p = w * 16 + lg * 4 + r;
      int d = ct * 16 + lr;
      attnout[((size_t)sel * 64 + p) * 512 + h * 64 + d] = f2bf(o[ct][r] * inv[r]);
    }
}

// ---------------- x1 = x + gate*proj (bf16), then LN2 + modulate -> x2 ----------------
// 4 rows per wave (consecutive, same spatial block) for memory-level parallelism.

__global__ __launch_bounds__(256) void x1ln2_k(const float* __restrict__ x,
    const u16* __restrict__ opout, const int* __restrict__ selmap,
    const float* __restrict__ mods, const float* __restrict__ nw,
    u16* __restrict__ x1, u16* __restrict__ x2) {
  int row0 = blockIdx.x * 16 + (threadIdx.x >> 6) * 4;   // aligned to 4
  int t = threadIdx.x & 63;
  int bt = row0 >> 15, s = row0 & 32767;
  int i1 = s >> 12, p1 = (s >> 10) & 3, i2 = (s >> 7) & 7,
      p2 = (s >> 5) & 3, i3 = (s >> 2) & 7, p3 = s & 3;  // p3 == 0 here
  int blk = (((i1 << 3) | i2) << 3) | i3;
  int m = selmap[(bt << 9) | blk];
  int p0 = (p1 << 4) | (p2 << 2) | p3;                   // rows -> p0..p0+3
  int d0 = t * 8;
  const float* src = x + (size_t)row0 * 512 + d0;
  float v[4][8];
  #pragma unroll
  for (int rr = 0; rr < 4; ++rr) {
    float4 a = *(const float4*)(src + rr * 512);
    float4 b = *(const float4*)(src + rr * 512 + 4);
    v[rr][0] = a.x; v[rr][1] = a.y; v[rr][2] = a.z; v[rr][3] = a.w;
    v[rr][4] = b.x; v[rr][5] = b.y; v[rr][6] = b.z; v[rr][7] = b.w;
  }
  const float* mb = mods + bt * 3072;
  float gm[8], sh2[8], sc2[8], wv[8];
  #pragma unroll
  for (int j = 0; j < 8; ++j) {
    gm[j] = mb[1024 + d0 + j]; sh2[j] = mb[1536 + d0 + j];
    sc2[j] = mb[2048 + d0 + j]; wv[j] = nw[d0 + j];
  }
  if (m >= 0) {
    const u16* op = opout + ((size_t)m * 64 + p0) * 512 + d0;
    #pragma unroll
    for (int rr = 0; rr < 4; ++rr) {
      u16 oh[8];
      *(uint4*)oh = *(const uint4*)(op + rr * 512);
      #pragma unroll
      for (int j = 0; j < 8; ++j) v[rr][j] += gm[j] * bf2f(oh[j]);
    }
  }
  #pragma unroll
  for (int rr = 0; rr < 4; ++rr) {
    u16 o1[8];
    #pragma unroll
    for (int j = 0; j < 8; ++j) o1[j] = f2bf(v[rr][j]);
    *(uint4*)(x1 + (size_t)(row0 + rr) * 512 + d0) = *(uint4*)o1;
    float sum = 0.f, sq = 0.f;
    #pragma unroll
    for (int j = 0; j < 8; ++j) { sum += v[rr][j]; sq += v[rr][j] * v[rr][j]; }
    #pragma unroll
    for (int mm = 1; mm < 64; mm <<= 1) {
      sum += __shfl_xor(sum, mm, 64);
      sq  += __shfl_xor(sq, mm, 64);
    }
    float mean = sum * (1.f / 512.f);
    float var = sq * (1.f / 512.f) - mean * mean;
    float rstd = rsqrtf(var + 1e-5f);
    u16 o[8];
    #pragma unroll
    for (int j = 0; j < 8; ++j) {
      float xn = (v[rr][j] - mean) * rstd * wv[j];
      o[j] = f2bf(xn * (1.f + sc2[j]) + sh2[j]);
    }
    *(uint4*)(x2 + (size_t)(row0 + rr) * 512 + d0) = *(uint4*)o;
  }
}

// ---------------- launcher ----------------

extern "C" void kernel_launch(void* const* d_in, const int* in_sizes, int n_in,
                              void* d_out, int out_size, void* d_ws, size_t ws_size,
                              hipStream_t stream) {
  const float* x    = (const float*)d_in[0];
  const float* c    = (const float*)d_in[1];
  const float* cosq = (const float*)d_in[2];
  const float* sinq = (const float*)d_in[3];
  const float* cosk = (const float*)d_in[4];
  const float* sink = (const float*)d_in[5];
  const int* nzb    = (const int*)d_in[6];
  const int* nbrs   = (const int*)d_in[7];
  const float* norm1_w = (const float*)d_in[11];
  const float* qkv_w   = (const float*)d_in[12];
  const float* out_w   = (const float*)d_in[13];
  const float* norm2_w = (const float*)d_in[14];
  const float* mlp_w1  = (const float*)d_in[15];
  const float* mlp_b1  = (const float*)d_in[16];
  const float* mlp_w2  = (const float*)d_in[17];
  const float* mlp_b2  = (const float*)d_in[18];
  const float* adaln_w = (const float*)d_in[19];
  const float* adaln_b = (const float*)d_in[20];
  const float* kv_e    = (const float*)d_in[21];
  float* outp = (float*)d_out;
  char* ws = (char*)d_ws;

  const size_t MB = 1024ull * 1024ull;
  // lifetime-based region map:
  u16*   qkvb    = (u16*)(ws + 0);            // [0,96)   qkv -> ropepack/vtrans
  u16*   opout   = (u16*)(ws + 0);            // [0,32)   outproj -> x1ln2 (bf16)
  u16*   hidden  = (u16*)(ws + 0);            // [0,256)  mlp1 -> mlp2
  u16*   xm      = (u16*)(ws + 96 * MB);      // [96,128) dead after qkv gemm
  u16*   attnout = (u16*)(ws + 96 * MB);      // [96,128) attn -> outproj
  u16*   qb      = (u16*)(ws + 128 * MB);     // [128,160) dead after attn
  u16*   kf      = (u16*)(ws + 160 * MB);     // [160,192) dead after attn
  u16*   vT      = (u16*)(ws + 192 * MB);     // [192,224) dead after attn
  u16*   x1      = (u16*)(ws + 256 * MB);     // [256,320) bf16 residual
  u16*   x2      = (u16*)(ws + 320 * MB);     // [320,384)
  char*  S0      = ws + 384 * MB;
  float* mods    = (float*)(S0);              // 24 KiB
  int*   selmap  = (int*)(S0 + 0x8000);       // 4 KiB
  u16*   kempty  = (u16*)(S0 + 0x10000);      // 64 KiB
  u16*   vTempty = (u16*)(S0 + 0x20000);      // 64 KiB
  u16*   qkvw_bf = (u16*)(S0 + 0x30000);              // 1.5 MiB
  u16*   outw_bf = qkvw_bf + (size_t)1536 * 512;      // 0.5 MiB
  u16*   w1_bf   = outw_bf + (size_t)512 * 512;       // 2 MiB
  u16*   w2_bf   = w1_bf + (size_t)2048 * 512;        // 2 MiB

  // prep
  selmap_k<<<1, 1024, 0, stream>>>(nzb, selmap);
  adaln_k<<<dim3(12, 2), 256, 0, stream>>>(c, adaln_w, adaln_b, mods);
  castw_k<<<768, 256, 0, stream>>>(qkv_w, qkvw_bf, 1536 * 512 / 4);
  castw_k<<<256, 256, 0, stream>>>(out_w, outw_bf, 512 * 512 / 4);
  castw_k<<<1024, 256, 0, stream>>>(mlp_w1, w1_bf, 2048 * 512 / 4);
  castw_k<<<1024, 256, 0, stream>>>(mlp_w2, w2_bf, 512 * 2048 / 4);
  kvempty_k<<<128, 256, 0, stream>>>(kv_e, cosk, sink, kempty, vTempty);

  // LN1 + modulate on selected rows (4 rows/wave)
  ln1_k<<<2048, 256, 0, stream>>>(x, norm1_w, mods, nzb, xm);

  // qkv = xm @ qkv_w^T (32768 x 1536 x 512): 256 x 12 tiles
  gemm128<0><<<3072, 256, 0, stream>>>(xm, qkvw_bf, 32768, 1536, 512, qkvb,
                                       nullptr, nullptr, nullptr, 12);
  // rope q/k, pack; transpose v
  ropepack_k<<<16384, 256, 0, stream>>>(qkvb, cosq, sinq, cosk, sink, qb, kf);
  vtrans_k<<<4096, 256, 0, stream>>>(qkvb, vT);

  // attention
  attn_k<<<4096, 256, 0, stream>>>(qb, kf, vT, kempty, vTempty, nbrs, selmap, attnout);

  // out projection (32768 x 512 x 512): 256 x 4 tiles -> bf16
  gemm128<0><<<1024, 256, 0, stream>>>(attnout, outw_bf, 32768, 512, 512, opout,
                                       nullptr, nullptr, nullptr, 4);

  // x1 = x + gate_msa*proj (bf16), LN2 + modulate -> x2 (4 rows/wave)
  x1ln2_k<<<4096, 256, 0, stream>>>(x, opout, selmap, mods, norm2_w, x1, x2);

  // MLP: (65536 x 2048 x 512) 512 x 16 tiles; (65536 x 512 x 2048) 512 x 4 tiles
  gemm128<2><<<8192, 256, 0, stream>>>(x2, w1_bf, 65536, 2048, 512, hidden,
                                       mlp_b1, nullptr, nullptr, 16);
  gemm128<3><<<2048, 256, 0, stream>>>(hidden, w2_bf, 65536, 512, 2048, outp,
                                       mlp_b2, x1, mods, 4);
}

// Round 16
// 782.826 us; speedup vs baseline: 1.4990x; 1.4990x over previous
//
#include <hip/hip_runtime.h>
#include <cstdint>
#include <cstddef>

typedef unsigned short u16;
typedef __attribute__((ext_vector_type(8))) __bf16 bf16x8;
typedef __attribute__((ext_vector_type(4))) float f32x4;

typedef __attribute__((address_space(1))) const void GAS;
typedef __attribute__((address_space(3))) void LAS;

__device__ __forceinline__ void gld_lds16(const void* g, void* l) {
  __builtin_amdgcn_global_load_lds((GAS*)g, (LAS*)l, 16, 0, 0);
}

__device__ __forceinline__ u16 f2bf(float f) {
  union { float f; unsigned u; } x; x.f = f;
  unsigned r = x.u + 0x7FFFu + ((x.u >> 16) & 1u);
  return (u16)(r >> 16);
}
__device__ __forceinline__ float bf2f(u16 s) {
  union { unsigned u; float f; } x; x.u = ((unsigned)s) << 16;
  return x.f;
}
__device__ __forceinline__ f32x4 mfma16(bf16x8 a, bf16x8 b, f32x4 c) {
  return __builtin_amdgcn_mfma_f32_16x16x32_bf16(a, b, c, 0, 0, 0);
}

// ---------------- small prep kernels ----------------

__global__ void selmap_k(const int* __restrict__ nzb, int* __restrict__ map) {
  int t = threadIdx.x;            // 1024 threads
  map[t] = -1;
  __syncthreads();
  if (t < 512) map[nzb[t]] = t;
}

__global__ __launch_bounds__(256) void castw_k(const float* __restrict__ in,
                                               u16* __restrict__ out, int n4) {
  int i = blockIdx.x * 256 + threadIdx.x;
  if (i >= n4) return;
  float4 v = ((const float4*)in)[i];
  u16 o[4] = {f2bf(v.x), f2bf(v.y), f2bf(v.z), f2bf(v.w)};
  ((uint2*)out)[i] = *(uint2*)o;
}

__global__ __launch_bounds__(256) void adaln_k(const float* __restrict__ c,
    const float* __restrict__ w, const float* __restrict__ b, float* __restrict__ mods) {
  int j = blockIdx.x * 256 + threadIdx.x;  // 0..3071
  int bt = blockIdx.y;
  const float4* cr = (const float4*)(c + bt * 512);
  const float4* wr = (const float4*)(w + (size_t)j * 512);
  float s = 0.f;
  #pragma unroll 4
  for (int k = 0; k < 128; ++k) {
    float4 a = wr[k], q = cr[k];
    s += a.x * q.x + a.y * q.y + a.z * q.z + a.w * q.w;
  }
  mods[bt * 3072 + j] = s + b[j];
}

// rope the shared empty-block K, copy/transpose empty V
__global__ __launch_bounds__(256) void kvempty_k(const float* __restrict__ kve,
    const float* __restrict__ cT, const float* __restrict__ sT,
    u16* __restrict__ kempty, u16* __restrict__ vTempty) {
  int T = blockIdx.x * 256 + threadIdx.x;  // 32768
  int h = T >> 12, p = (T >> 6) & 63, d = T & 63;
  float kv = kve[p * 1024 + h * 64 + d];
  float pv = kve[p * 1024 + h * 64 + (d ^ 32)];
  float cs = cT[p * 64 + d], sn = sT[p * 64 + d];
  float r = kv * cs + ((d < 32) ? -pv : pv) * sn;
  kempty[(h * 64 + p) * 64 + d] = f2bf(r);
  vTempty[(h * 64 + d) * 64 + p] = f2bf(kve[p * 1024 + 512 + h * 64 + d]);
}

// ---------------- LN1 + modulate + block-gather, 4 rows/wave ----------------

__global__ __launch_bounds__(256) void ln1_k(const float* __restrict__ x,
    const float* __restrict__ nw, const float* __restrict__ mods,
    const int* __restrict__ nzb, u16* __restrict__ xm) {
  int row0 = blockIdx.x * 16 + (threadIdx.x >> 6) * 4;  // p aligned to 4
  int t = threadIdx.x & 63;
  int sel = row0 >> 6, p = row0 & 63;
  int g = nzb[sel];
  int bt = g >> 9, blk = g & 511;
  int s = (blk >> 6) * 4096 + (p >> 4) * 1024 + ((blk >> 3) & 7) * 128
        + ((p >> 2) & 3) * 32 + (blk & 7) * 4 + (p & 3);
  const float* src = x + ((size_t)bt * 32768 + s) * 512;   // rows s..s+3 consecutive
  int d0 = t * 8;
  float v[4][8];
  #pragma unroll
  for (int rr = 0; rr < 4; ++rr) {
    float4 a = *(const float4*)(src + rr * 512 + d0);
    float4 b = *(const float4*)(src + rr * 512 + d0 + 4);
    v[rr][0] = a.x; v[rr][1] = a.y; v[rr][2] = a.z; v[rr][3] = a.w;
    v[rr][4] = b.x; v[rr][5] = b.y; v[rr][6] = b.z; v[rr][7] = b.w;
  }
  const float* mb = mods + bt * 3072;
  float wv[8], sh[8], sc[8];
  #pragma unroll
  for (int j = 0; j < 8; ++j) {
    wv[j] = nw[d0 + j]; sh[j] = mb[d0 + j]; sc[j] = mb[512 + d0 + j];
  }
  #pragma unroll
  for (int rr = 0; rr < 4; ++rr) {
    float sum = 0.f, sq = 0.f;
    #pragma unroll
    for (int j = 0; j < 8; ++j) { sum += v[rr][j]; sq += v[rr][j] * v[rr][j]; }
    #pragma unroll
    for (int m = 1; m < 64; m <<= 1) {
      sum += __shfl_xor(sum, m, 64);
      sq  += __shfl_xor(sq, m, 64);
    }
    float mean = sum * (1.f / 512.f);
    float var = sq * (1.f / 512.f) - mean * mean;
    float rstd = rsqrtf(var + 1e-5f);
    u16 o[8];
    #pragma unroll
    for (int j = 0; j < 8; ++j) {
      float xn = (v[rr][j] - mean) * rstd * wv[j];
      o[j] = f2bf(xn * (1.f + sc[j]) + sh[j]);
    }
    *(uint4*)(xm + (size_t)(row0 + rr) * 512 + d0) = *(uint4*)o;
  }
}

// ---------------- 128x128 bf16 GEMM, BK=32, dbuf, counted vmcnt, 4 waves ----------------
// 16x16x32 MFMA (conflict-free; 32x32x16 at BK=32 is 4-way conflicted, R14).
// (256,4) ONLY: with 256-thread blocks, any higher bound forces 2 blocks/SIMD
// -> VGPR cap <= 64/48 -> spill (R15: (256,5) gave VGPR 48, 660MB scratch).
// NON-CHAINED (bn-fast tile order keeps A-panel sharers concurrently resident
// -> L2-hit reuse; chaining thrashed L3, R7/R8). XCD-swizzled tile id.
// Swizzle: chunk j of row r stored at pos = j ^ ((r>>1)&3)  (2-way max = free).
// EPI: 0 store bf16; 2 +bias+sigmoid-gelu bf16; 3 +bias, out = bf2f(x1)+gate*val

template <int EPI>
__global__ __launch_bounds__(256, 4) void gemm128(const u16* __restrict__ A,
    const u16* __restrict__ W, int M, int N, int K, void* __restrict__ outp,
    const float* __restrict__ bias, const u16* __restrict__ x1,
    const float* __restrict__ mods, int NB) {
  __shared__ u16 L[2][8192];             // [buf][A:4096 | B:4096]
  const int nwg = gridDim.x;
  const int cpx = nwg >> 3;
  const int tile = ((int)blockIdx.x & 7) * cpx + ((int)blockIdx.x >> 3);
  const int bm = (tile / NB) * 128, bn = (tile % NB) * 128;
  const int tid = threadIdx.x;
  const int w = tid >> 6, l = tid & 63, lr = l & 15, lg = l >> 4;
  const int wr = w >> 1, wc = w & 1;

  // staging: slot s -> row s>>2, pos s&3; global chunk j = (s&3) ^ ((s>>3)&3)
  const int s0 = tid, s1 = 256 + tid;
  const int rA0 = s0 >> 2, j0 = (s0 & 3) ^ ((s0 >> 3) & 3);
  const int rA1 = s1 >> 2, j1 = (s1 & 3) ^ ((s1 >> 3) & 3);
  const u16* gA0 = A + (size_t)(bm + rA0) * K + j0 * 8;
  const u16* gA1 = A + (size_t)(bm + rA1) * K + j1 * 8;
  const u16* gB0 = W + (size_t)(bn + rA0) * K + j0 * 8;
  const u16* gB1 = W + (size_t)(bn + rA1) * K + j1 * 8;

  f32x4 acc[4][4];
  #pragma unroll
  for (int i = 0; i < 4; ++i)
    #pragma unroll
    for (int j = 0; j < 4; ++j) acc[i][j] = (f32x4){0.f, 0.f, 0.f, 0.f};

  auto STAGE = [&](int kt, int buf) {
    u16* lb = &L[buf][0];
    gld_lds16(gA0 + (size_t)kt * 32, lb + s0 * 8);
    gld_lds16(gA1 + (size_t)kt * 32, lb + s1 * 8);
    gld_lds16(gB0 + (size_t)kt * 32, lb + 4096 + s0 * 8);
    gld_lds16(gB1 + (size_t)kt * 32, lb + 4096 + s1 * 8);
  };
  auto COMPUTE = [&](int buf) {
    const u16* base = &L[buf][0];
    bf16x8 bfr[4];
    #pragma unroll
    for (int nf = 0; nf < 4; ++nf) {
      int rB = wc * 64 + nf * 16 + lr;
      bfr[nf] = *(const bf16x8*)(base + 4096 + rB * 32 + ((lg ^ ((rB >> 1) & 3)) << 3));
    }
    __builtin_amdgcn_s_setprio(1);
    #pragma unroll
    for (int mf = 0; mf < 4; ++mf) {
      int rA = wr * 64 + mf * 16 + lr;
      bf16x8 a = *(const bf16x8*)(base + rA * 32 + ((lg ^ ((rA >> 1) & 3)) << 3));
      #pragma unroll
      for (int nf = 0; nf < 4; ++nf)
        acc[mf][nf] = mfma16(a, bfr[nf], acc[mf][nf]);
    }
    __builtin_amdgcn_s_setprio(0);
  };

  const int NT = K >> 5;
  STAGE(0, 0);
  for (int t = 0; t < NT; ++t) {
    if (t + 1 < NT) {
      STAGE(t + 1, (t + 1) & 1);
      asm volatile("s_waitcnt vmcnt(4)" ::: "memory");
    } else {
      asm volatile("s_waitcnt vmcnt(0)" ::: "memory");
    }
    __builtin_amdgcn_sched_barrier(0);
    __builtin_amdgcn_s_barrier();
    asm volatile("" ::: "memory");
    COMPUTE(t & 1);
    asm volatile("" ::: "memory");
    __builtin_amdgcn_s_barrier();
    __builtin_amdgcn_sched_barrier(0);
  }

  const int row0 = bm + wr * 64, col0 = bn + wc * 64;
  #pragma unroll
  for (int mf = 0; mf < 4; ++mf) {
    #pragma unroll
    for (int nf = 0; nf < 4; ++nf) {
      #pragma unroll
      for (int j = 0; j < 4; ++j) {
        int row = row0 + mf * 16 + lg * 4 + j;
        int col = col0 + nf * 16 + lr;
        float v = acc[mf][nf][j];
        if constexpr (EPI == 0) {
          ((u16*)outp)[(size_t)row * N + col] = f2bf(v);
        } else if constexpr (EPI == 2) {
          v += bias[col];
          // sigmoid-GELU: v*sigmoid(1.702v) (|diff| vs tanh-GELU < ~0.02)
          float sg = 1.f / (1.f + __expf(-1.702f * v));
          ((u16*)outp)[(size_t)row * N + col] = f2bf(v * sg);
        } else {
          v += bias[col];
          int bt = row >> 15;
          float gate = mods[bt * 3072 + 2560 + col];
          ((float*)outp)[(size_t)row * 512 + col] =
              bf2f(x1[(size_t)row * 512 + col]) + gate * v;
        }
      }
    }
  }
}

// ---------------- rope + pack q/k into [sel][h][p][d] ----------------

__global__ __launch_bounds__(256) void ropepack_k(const u16* __restrict__ qkv,
    const float* __restrict__ cq, const float* __restrict__ sq,
    const float* __restrict__ ck, const float* __restrict__ sk,
    u16* __restrict__ qb, u16* __restrict__ kb) {
  int T = blockIdx.x * 256 + threadIdx.x;  // 32768 * 128
  int row = T >> 7, oct = T & 127;
  int c0 = oct * 8;
  int sel = row >> 6, p = row & 63;
  int isk = (c0 >= 512);
  int chn = c0 & 511;
  int h = chn >> 6, d0 = chn & 63;
  int lower = (d0 < 32);
  const u16* base = qkv + (size_t)row * 1536 + (isk ? 512 : 0) + h * 64;
  u16 vm[8], vp[8];
  *(uint4*)vm = *(const uint4*)(base + d0);
  *(uint4*)vp = *(const uint4*)(base + (d0 ^ 32));
  const float* cT = (isk ? ck : cq) + p * 64 + d0;
  const float* sT = (isk ? sk : sq) + p * 64 + d0;
  float scale = isk ? 1.f : 0.125f;  // fold 1/sqrt(dh) into q
  u16 o[8];
  #pragma unroll
  for (int j = 0; j < 8; ++j) {
    float a = bf2f(vm[j]), b = bf2f(vp[j]);
    float r = a * cT[j] + (lower ? -b : b) * sT[j];
    o[j] = f2bf(r * scale);
  }
  u16* dst = (isk ? kb : qb) + (((size_t)sel * 8 + h) * 64 + p) * 64 + d0;
  *(uint4*)dst = *(uint4*)o;
}

// ---------------- v transpose: qkv v-part -> vT [sel][h][d][p] ----------------

__global__ __launch_bounds__(256) void vtrans_k(const u16* __restrict__ qkv,
                                                u16* __restrict__ vT) {
  __shared__ u16 tb[64 * 65];
  int sel = blockIdx.x >> 3, h = blockIdx.x & 7;
  int tid = threadIdx.x;
  int p = tid >> 2, q16 = (tid & 3) * 16;
  const u16* src = qkv + (size_t)(sel * 64 + p) * 1536 + 1024 + h * 64 + q16;
  u16 ld[16];
  *(uint4*)&ld[0] = *(const uint4*)src;
  *(uint4*)&ld[8] = *(const uint4*)(src + 8);
  #pragma unroll
  for (int j = 0; j < 16; ++j) tb[p * 65 + q16 + j] = ld[j];
  __syncthreads();
  int d = tid >> 2, po = (tid & 3) * 16;
  u16 o[16];
  #pragma unroll
  for (int j = 0; j < 16; ++j) o[j] = tb[(po + j) * 65 + d];
  u16* dst = vT + (((size_t)sel * 8 + h) * 64 + d) * 64 + po;
  *(uint4*)dst = *(uint4*)&o[0];
  *(uint4*)(dst + 8) = *(uint4*)&o[8];
}

// ---------------- attention: flash over neighbors, K staged in LDS ----------------
// R3-proven structure: K double-buffered in LDS (XOR-swizzled via pre-swizzled
// global src), counted vmcnt(2), raw barriers; V direct-global; online softmax.
// (256,4) ONLY: any higher min-waves bound spills (R10: (256,8) VGPR->32;
// R12: (256,6) VGPR->40, scratch FETCH 304MB). Natural VGPR=64 at (256,4).

__global__ __launch_bounds__(256, 4) void attn_k(const u16* __restrict__ qbuf,
    const u16* __restrict__ kfull, const u16* __restrict__ vT,
    const u16* __restrict__ kempty, const u16* __restrict__ vTempty,
    const int* __restrict__ nbrs, const int* __restrict__ selmap,
    u16* __restrict__ attnout) {
  __shared__ u16 KB[2][4096];        // 16 KiB, K tile [64 k][64 d], chunk^=(row&7)
  __shared__ u16 Pl[4][16][72];      // 9.2 KiB, per-wave P
  int bid = blockIdx.x;
  int swz = (bid & 7) * 512 + (bid >> 3);   // XCD-chunked (4096 % 8 == 0, bijective)
  int sel = swz >> 3, h = swz & 7;
  int tid = threadIdx.x;
  int w = tid >> 6, l = tid & 63, lr = l & 15, lg = l >> 4;

  int mmv[7];
  #pragma unroll
  for (int n = 0; n < 7; ++n) mmv[n] = selmap[nbrs[sel * 7 + n]];

  const u16* qg = qbuf + (((size_t)sel * 8 + h) * 64 + w * 16) * 64;
  bf16x8 qf0 = *(const bf16x8*)(qg + lr * 64 + lg * 8);
  bf16x8 qf1 = *(const bf16x8*)(qg + lr * 64 + 32 + lg * 8);

  // staging: LDS slot s = i*256+tid holds K[row=s>>3][chunk=(s&7)^(row&7)]
  int srow = tid >> 3;
  int soff = srow * 64 + (((tid & 7) ^ (srow & 7)) << 3);  // u16 units; i=1: +2048
  size_t hoff = (size_t)h * 4096;

  {
    const u16* kp = (mmv[0] >= 0) ? kfull + (size_t)mmv[0] * 32768 + hoff
                                  : kempty + hoff;
    gld_lds16(kp + soff, &KB[0][w * 512]);
    gld_lds16(kp + soff + 2048, &KB[0][2048 + w * 512]);
  }

  f32x4 o[4];
  float mrun[4], lrun[4];
  #pragma unroll
  for (int ct = 0; ct < 4; ++ct) o[ct] = (f32x4){0.f, 0.f, 0.f, 0.f};
  #pragma unroll
  for (int r = 0; r < 4; ++r) { mrun[r] = -1e30f; lrun[r] = 0.f; }

  #pragma unroll
  for (int n = 0; n < 7; ++n) {
    if (n < 6) {
      const u16* kp = (mmv[n + 1] >= 0) ? kfull + (size_t)mmv[n + 1] * 32768 + hoff
                                        : kempty + hoff;
      int b = (n + 1) & 1;
      gld_lds16(kp + soff, &KB[b][w * 512]);
      gld_lds16(kp + soff + 2048, &KB[b][2048 + w * 512]);
      asm volatile("s_waitcnt vmcnt(2)" ::: "memory");
    } else {
      asm volatile("s_waitcnt vmcnt(0)" ::: "memory");
    }
    __builtin_amdgcn_s_barrier();
    __builtin_amdgcn_sched_barrier(0);

    const u16* kl = &KB[n & 1][0];
    const u16* vp = (mmv[n] >= 0) ? vT + (size_t)mmv[n] * 32768 + hoff
                                  : vTempty + hoff;
    // QK^T for this neighbor
    f32x4 s4[4];
    int xr = lr & 7;
    #pragma unroll
    for (int ct = 0; ct < 4; ++ct) {
      int row = ct * 16 + lr;
      bf16x8 b0 = *(const bf16x8*)(kl + row * 64 + ((lg ^ xr) << 3));
      bf16x8 b1 = *(const bf16x8*)(kl + row * 64 + (((lg + 4) ^ xr) << 3));
      f32x4 z = (f32x4){0.f, 0.f, 0.f, 0.f};
      z = mfma16(qf0, b0, z);
      z = mfma16(qf1, b1, z);
      s4[ct] = z;
    }
    // online softmax update
    float rmax[4], sc[4], rs[4];
    #pragma unroll
    for (int r = 0; r < 4; ++r)
      rmax[r] = fmaxf(fmaxf(s4[0][r], s4[1][r]), fmaxf(s4[2][r], s4[3][r]));
    #pragma unroll
    for (int r = 0; r < 4; ++r) {
      #pragma unroll
      for (int ms = 1; ms < 16; ms <<= 1)
        rmax[r] = fmaxf(rmax[r], __shfl_xor(rmax[r], ms, 64));
      float mn = fmaxf(mrun[r], rmax[r]);
      sc[r] = __expf(mrun[r] - mn);
      mrun[r] = mn;
      rs[r] = 0.f;
    }
    #pragma unroll
    for (int ct = 0; ct < 4; ++ct)
      #pragma unroll
      for (int r = 0; r < 4; ++r) {
        float e = __expf(s4[ct][r] - mrun[r]);
        s4[ct][r] = e;
        rs[r] += e;
      }
    #pragma unroll
    for (int r = 0; r < 4; ++r) {
      #pragma unroll
      for (int ms = 1; ms < 16; ms <<= 1) rs[r] += __shfl_xor(rs[r], ms, 64);
      lrun[r] = lrun[r] * sc[r] + rs[r];
    }
    #pragma unroll
    for (int ct = 0; ct < 4; ++ct)
      #pragma unroll
      for (int r = 0; r < 4; ++r) o[ct][r] *= sc[r];
    // P -> LDS (wave-local), then PV with direct-global V
    #pragma unroll
    for (int ct = 0; ct < 4; ++ct)
      #pragma unroll
      for (int r = 0; r < 4; ++r)
        Pl[w][lg * 4 + r][ct * 16 + lr] = f2bf(s4[ct][r]);
    asm volatile("s_waitcnt lgkmcnt(0)" ::: "memory");
    __builtin_amdgcn_sched_barrier(0);
    bf16x8 pa0 = *(const bf16x8*)&Pl[w][lr][lg * 8];
    bf16x8 pa1 = *(const bf16x8*)&Pl[w][lr][32 + lg * 8];
    #pragma unroll
    for (int ct = 0; ct < 4; ++ct) {
      bf16x8 v0 = *(const bf16x8*)(vp + (ct * 16 + lr) * 64 + lg * 8);
      bf16x8 v1 = *(const bf16x8*)(vp + (ct * 16 + lr) * 64 + 32 + lg * 8);
      o[ct] = mfma16(pa0, v0, o[ct]);
      o[ct] = mfma16(pa1, v1, o[ct]);
    }
    asm volatile("" ::: "memory");
    __builtin_amdgcn_s_barrier();     // KB[n&1] free for restage at iter n+1
    __builtin_amdgcn_sched_barrier(0);
  }

  float inv[4];
  #pragma unroll
  for (int r = 0; r < 4; ++r) inv[r] = 1.f / lrun[r];
  #pragma unroll
  for (int ct = 0; ct < 4; ++ct)
    #pragma unroll
    for (int r = 0; r < 4; ++r) {
      int p = w * 16 + lg * 4 + r;
      int d = ct * 16 + lr;
      attnout[((size_t)sel * 64 + p) * 512 + h * 64 + d] = f2bf(o[ct][r] * inv[r]);
    }
}

// ---------------- x1 = x + gate*proj (bf16), then LN2 + modulate -> x2 ----------------
// 4 rows per wave (consecutive, same spatial block) for memory-level parallelism.

__global__ __launch_bounds__(256) void x1ln2_k(const float* __restrict__ x,
    const u16* __restrict__ opout, const int* __restrict__ selmap,
    const float* __restrict__ mods, const float* __restrict__ nw,
    u16* __restrict__ x1, u16* __restrict__ x2) {
  int row0 = blockIdx.x * 16 + (threadIdx.x >> 6) * 4;   // aligned to 4
  int t = threadIdx.x & 63;
  int bt = row0 >> 15, s = row0 & 32767;
  int i1 = s >> 12, p1 = (s >> 10) & 3, i2 = (s >> 7) & 7,
      p2 = (s >> 5) & 3, i3 = (s >> 2) & 7, p3 = s & 3;  // p3 == 0 here
  int blk = (((i1 << 3) | i2) << 3) | i3;
  int m = selmap[(bt << 9) | blk];
  int p0 = (p1 << 4) | (p2 << 2) | p3;                   // rows -> p0..p0+3
  int d0 = t * 8;
  const float* src = x + (size_t)row0 * 512 + d0;
  float v[4][8];
  #pragma unroll
  for (int rr = 0; rr < 4; ++rr) {
    float4 a = *(const float4*)(src + rr * 512);
    float4 b = *(const float4*)(src + rr * 512 + 4);
    v[rr][0] = a.x; v[rr][1] = a.y; v[rr][2] = a.z; v[rr][3] = a.w;
    v[rr][4] = b.x; v[rr][5] = b.y; v[rr][6] = b.z; v[rr][7] = b.w;
  }
  const float* mb = mods + bt * 3072;
  float gm[8], sh2[8], sc2[8], wv[8];
  #pragma unroll
  for (int j = 0; j < 8; ++j) {
    gm[j] = mb[1024 + d0 + j]; sh2[j] = mb[1536 + d0 + j];
    sc2[j] = mb[2048 + d0 + j]; wv[j] = nw[d0 + j];
  }
  if (m >= 0) {
    const u16* op = opout + ((size_t)m * 64 + p0) * 512 + d0;
    #pragma unroll
    for (int rr = 0; rr < 4; ++rr) {
      u16 oh[8];
      *(uint4*)oh = *(const uint4*)(op + rr * 512);
      #pragma unroll
      for (int j = 0; j < 8; ++j) v[rr][j] += gm[j] * bf2f(oh[j]);
    }
  }
  #pragma unroll
  for (int rr = 0; rr < 4; ++rr) {
    u16 o1[8];
    #pragma unroll
    for (int j = 0; j < 8; ++j) o1[j] = f2bf(v[rr][j]);
    *(uint4*)(x1 + (size_t)(row0 + rr) * 512 + d0) = *(uint4*)o1;
    float sum = 0.f, sq = 0.f;
    #pragma unroll
    for (int j = 0; j < 8; ++j) { sum += v[rr][j]; sq += v[rr][j] * v[rr][j]; }
    #pragma unroll
    for (int mm = 1; mm < 64; mm <<= 1) {
      sum += __shfl_xor(sum, mm, 64);
      sq  += __shfl_xor(sq, mm, 64);
    }
    float mean = sum * (1.f / 512.f);
    float var = sq * (1.f / 512.f) - mean * mean;
    float rstd = rsqrtf(var + 1e-5f);
    u16 o[8];
    #pragma unroll
    for (int j = 0; j < 8; ++j) {
      float xn = (v[rr][j] - mean) * rstd * wv[j];
      o[j] = f2bf(xn * (1.f + sc2[j]) + sh2[j]);
    }
    *(uint4*)(x2 + (size_t)(row0 + rr) * 512 + d0) = *(uint4*)o;
  }
}

// ---------------- launcher ----------------

extern "C" void kernel_launch(void* const* d_in, const int* in_sizes, int n_in,
                              void* d_out, int out_size, void* d_ws, size_t ws_size,
                              hipStream_t stream) {
  const float* x    = (const float*)d_in[0];
  const float* c    = (const float*)d_in[1];
  const float* cosq = (const float*)d_in[2];
  const float* sinq = (const float*)d_in[3];
  const float* cosk = (const float*)d_in[4];
  const float* sink = (const float*)d_in[5];
  const int* nzb    = (const int*)d_in[6];
  const int* nbrs   = (const int*)d_in[7];
  const float* norm1_w = (const float*)d_in[11];
  const float* qkv_w   = (const float*)d_in[12];
  const float* out_w   = (const float*)d_in[13];
  const float* norm2_w = (const float*)d_in[14];
  const float* mlp_w1  = (const float*)d_in[15];
  const float* mlp_b1  = (const float*)d_in[16];
  const float* mlp_w2  = (const float*)d_in[17];
  const float* mlp_b2  = (const float*)d_in[18];
  const float* adaln_w = (const float*)d_in[19];
  const float* adaln_b = (const float*)d_in[20];
  const float* kv_e    = (const float*)d_in[21];
  float* outp = (float*)d_out;
  char* ws = (char*)d_ws;

  const size_t MB = 1024ull * 1024ull;
  // lifetime-based region map:
  u16*   qkvb    = (u16*)(ws + 0);            // [0,96)   qkv -> ropepack/vtrans
  u16*   opout   = (u16*)(ws + 0);            // [0,32)   outproj -> x1ln2 (bf16)
  u16*   hidden  = (u16*)(ws + 0);            // [0,256)  mlp1 -> mlp2
  u16*   xm      = (u16*)(ws + 96 * MB);      // [96,128) dead after qkv gemm
  u16*   attnout = (u16*)(ws + 96 * MB);      // [96,128) attn -> outproj
  u16*   qb      = (u16*)(ws + 128 * MB);     // [128,160) dead after attn
  u16*   kf      = (u16*)(ws + 160 * MB);     // [160,192) dead after attn
  u16*   vT      = (u16*)(ws + 192 * MB);     // [192,224) dead after attn
  u16*   x1      = (u16*)(ws + 256 * MB);     // [256,320) bf16 residual
  u16*   x2      = (u16*)(ws + 320 * MB);     // [320,384)
  char*  S0      = ws + 384 * MB;
  float* mods    = (float*)(S0);              // 24 KiB
  int*   selmap  = (int*)(S0 + 0x8000);       // 4 KiB
  u16*   kempty  = (u16*)(S0 + 0x10000);      // 64 KiB
  u16*   vTempty = (u16*)(S0 + 0x20000);      // 64 KiB
  u16*   qkvw_bf = (u16*)(S0 + 0x30000);              // 1.5 MiB
  u16*   outw_bf = qkvw_bf + (size_t)1536 * 512;      // 0.5 MiB
  u16*   w1_bf   = outw_bf + (size_t)512 * 512;       // 2 MiB
  u16*   w2_bf   = w1_bf + (size_t)2048 * 512;        // 2 MiB

  // prep
  selmap_k<<<1, 1024, 0, stream>>>(nzb, selmap);
  adaln_k<<<dim3(12, 2), 256, 0, stream>>>(c, adaln_w, adaln_b, mods);
  castw_k<<<768, 256, 0, stream>>>(qkv_w, qkvw_bf, 1536 * 512 / 4);
  castw_k<<<256, 256, 0, stream>>>(out_w, outw_bf, 512 * 512 / 4);
  castw_k<<<1024, 256, 0, stream>>>(mlp_w1, w1_bf, 2048 * 512 / 4);
  castw_k<<<1024, 256, 0, stream>>>(mlp_w2, w2_bf, 512 * 2048 / 4);
  kvempty_k<<<128, 256, 0, stream>>>(kv_e, cosk, sink, kempty, vTempty);

  // LN1 + modulate on selected rows (4 rows/wave)
  ln1_k<<<2048, 256, 0, stream>>>(x, norm1_w, mods, nzb, xm);

  // qkv = xm @ qkv_w^T (32768 x 1536 x 512): 256 x 12 tiles
  gemm128<0><<<3072, 256, 0, stream>>>(xm, qkvw_bf, 32768, 1536, 512, qkvb,
                                       nullptr, nullptr, nullptr, 12);
  // rope q/k, pack; transpose v
  ropepack_k<<<16384, 256, 0, stream>>>(qkvb, cosq, sinq, cosk, sink, qb, kf);
  vtrans_k<<<4096, 256, 0, stream>>>(qkvb, vT);

  // attention
  attn_k<<<4096, 256, 0, stream>>>(qb, kf, vT, kempty, vTempty, nbrs, selmap, attnout);

  // out projection (32768 x 512 x 512): 256 x 4 tiles -> bf16
  gemm128<0><<<1024, 256, 0, stream>>>(attnout, outw_bf, 32768, 512, 512, opout,
                                       nullptr, nullptr, nullptr, 4);

  // x1 = x + gate_msa*proj (bf16), LN2 + modulate -> x2 (4 rows/wave)
  x1ln2_k<<<4096, 256, 0, stream>>>(x, opout, selmap, mods, norm2_w, x1, x2);

  // MLP: (65536 x 2048 x 512) 512 x 16 tiles; (65536 x 512 x 2048) 512 x 4 tiles
  gemm128<2><<<8192, 256, 0, stream>>>(x2, w1_bf, 65536, 2048, 512, hidden,
                                       mlp_b1, nullptr, nullptr, 16);
  gemm128<3><<<2048, 256, 0, stream>>>(hidden, w2_bf, 65536, 512, 2048, outp,
                                       mlp_b2, x1, mods, 4);
}